// Round 8
// baseline (136.151 us; speedup 1.0000x reference)
//
#include <hip/hip_runtime.h>
#include <stdint.h>

#define T 49
#define CCH 256

typedef __bf16 bf16x8 __attribute__((ext_vector_type(8)));
typedef float f32x4 __attribute__((ext_vector_type(4)));

static __device__ __forceinline__ unsigned short f2bf(float f){
  __bf16 h = (__bf16)f;
  return __builtin_bit_cast(unsigned short, h);
}
static __device__ __forceinline__ float bf2f(unsigned short h){
  return __builtin_bit_cast(float, ((uint32_t)h) << 16);
}
static __device__ __forceinline__ uint32_t pk2(float a, float b){
  return (uint32_t)f2bf(a) | ((uint32_t)f2bf(b) << 16);
}
static __device__ __forceinline__ f32x4 mfma16(bf16x8 a, bf16x8 b, f32x4 c){
  return __builtin_amdgcn_mfma_f32_16x16x32_bf16(a, b, c, 0, 0, 0);
}
// XOR-swizzle of 16B chunks within 128B, keyed by low 3 bits of the row index.
#define SWZ(row) ((((row) & 7) << 4))

// Build an MFMA A/B-frag (lane: n/m=lo, k=8g+e) from packed C-layout words.
static __device__ __forceinline__ bf16x8 build_frag(uint32_t lo_w0, uint32_t lo_w1,
                                                    uint32_t hi_w0, uint32_t hi_w1,
                                                    int srcA, int srcB, bool use_hi){
  uint32_t a0 = (uint32_t)__shfl((int)lo_w0, srcA, 64);
  uint32_t c0 = (uint32_t)__shfl((int)hi_w0, srcA, 64);
  uint32_t a1 = (uint32_t)__shfl((int)lo_w1, srcA, 64);
  uint32_t c1 = (uint32_t)__shfl((int)hi_w1, srcA, 64);
  uint32_t a2 = (uint32_t)__shfl((int)lo_w0, srcB, 64);
  uint32_t c2 = (uint32_t)__shfl((int)hi_w0, srcB, 64);
  uint32_t a3 = (uint32_t)__shfl((int)lo_w1, srcB, 64);
  uint32_t c3 = (uint32_t)__shfl((int)hi_w1, srcB, 64);
  uint4 u = use_hi ? make_uint4(c0, c1, c2, c3) : make_uint4(a0, a1, a2, a3);
  return __builtin_bit_cast(bf16x8, u);
}

// ---------------- prep kernels ----------------

__global__ void prep_wqkvT(const float* __restrict__ wq, const float* __restrict__ wk,
                           const float* __restrict__ wv, unsigned short* __restrict__ out){
  int bk = blockIdx.x;            // 0..767
  int p = bk >> 8, kk = bk & 255;
  int n = threadIdx.x;
  const float* w = (p == 0) ? wq : (p == 1 ? wk : wv);
  float scl = (p == 0) ? 0.17677669529663687f : 1.0f;
  out[(size_t)(p * 256 + n) * 256 + kk] = f2bf(w[kk * 256 + n] * scl);
}

__global__ void prep_wodT(const float* __restrict__ wo, const float* __restrict__ dw,
                          unsigned short* __restrict__ out){
  int hd = blockIdx.x;            // 0..255
  int c = threadIdx.x;            // 0..255
  float s = 0.f;
  for (int cp = 0; cp < 256; ++cp) s = fmaf(wo[hd * 256 + cp], dw[cp * 256 + c], s);
  out[(size_t)c * 256 + hd] = f2bf(s);
}

// block 0: bqkv (q-scaled) + bod
// blocks 1..8: biasP[h*4096 + jt*1024 + nt*256 + g*64 + lo*4 + r] = bias(j=16jt+4g+r, i=16nt+lo)
__global__ void prep_misc(const int* __restrict__ rp, const float* __restrict__ btab,
                          const float* __restrict__ bq, const float* __restrict__ bk,
                          const float* __restrict__ bv, const float* __restrict__ bo,
                          const float* __restrict__ dwm, const float* __restrict__ db,
                          unsigned short* __restrict__ biasP, float* __restrict__ bqkv,
                          float* __restrict__ bod){
  int t = threadIdx.x;
  if (blockIdx.x == 0){
    for (int idx = t; idx < 768; idx += 256){
      int p = idx >> 8, n = idx & 255;
      float v = (p == 0) ? bq[n] * 0.17677669529663687f : (p == 1 ? bk[n] : bv[n]);
      bqkv[idx] = v;
    }
    float s = db[t];
    for (int cp = 0; cp < 256; ++cp) s = fmaf(bo[cp], dwm[cp * 256 + t], s);
    bod[t] = s;
  } else {
    int h = blockIdx.x - 1;
    for (int idx = t; idx < 4096; idx += 256){
      int r  = idx & 3;
      int lo = (idx >> 2) & 15;
      int g  = (idx >> 6) & 3;
      int nt = (idx >> 8) & 3;
      int jt = idx >> 10;
      int j = 16 * jt + 4 * g + r;
      int i = 16 * nt + lo;
      float v;
      if (j >= T) v = -1e30f;
      else if (i >= T) v = 0.f;
      else {
        int r0 = rp[i * 49 + j];
        int r1 = rp[2401 + i * 49 + j];
        v = btab[h * 169 + r0 * 13 + r1];
      }
      biasP[h * 4096 + idx] = f2bf(v);
    }
  }
}

// ---------------- fused main kernel ----------------
// 1 block = 1 window, 512 threads, wave = head. LDS 64 KB (xs 32, vts 32) ->
// 2 blocks/CU (LDS-capped); at 4 waves/SIMD the reg budget is 128/lane, so
// the free ~68 regs are spent on ILP: merged k+q pass (shared bx reads, 64
// AGPR acc), attention in nt-pairs (two softmax chains in flight), pre-barrier
// weight issue, full bias preload.
__launch_bounds__(512, 4)
__global__ void wmsa_main(const float* __restrict__ x,
                          const unsigned short* __restrict__ wqkvT,
                          const unsigned short* __restrict__ wodT,
                          const unsigned short* __restrict__ biasP,
                          const float* __restrict__ bqkv,
                          const float* __restrict__ bod,
                          float* __restrict__ y){
  __shared__ unsigned short xs[64 * 256];      // 32 KB
  __shared__ unsigned short vts[8 * 32 * 64];  // 32 KB

  const int b    = blockIdx.x;
  const int tid  = threadIdx.x;
  const int h    = tid >> 6;       // wave == head
  const int lane = tid & 63;
  const int g    = lane >> 4;
  const int lo   = lane & 15;
  char* xs_c = (char*)xs;

  // ---- stage x -> xs; overlap: issue x loads, then v-weight chunk 0 loads ----
  const float* xb = x + (size_t)b * T * CCH;
  float4 vv[8];
  #pragma unroll
  for (int k2 = 0; k2 < 8; ++k2){
    int idx = tid + k2 * 512;
    int row = idx >> 6, c4 = idx & 63;
    vv[k2] = make_float4(0.f, 0.f, 0.f, 0.f);
    if (row < T) vv[k2] = reinterpret_cast<const float4*>(xb)[row * 64 + c4];
  }
  bf16x8 wv[2][4];   // v-weight frags for kt=0..3, issued before the barrier
  #pragma unroll
  for (int nt = 0; nt < 2; ++nt)
    #pragma unroll
    for (int q4 = 0; q4 < 4; ++q4)
      wv[nt][q4] = *reinterpret_cast<const bf16x8*>(
          wqkvT + (size_t)(512 + h * 32 + 16 * nt + lo) * 256 + q4 * 32 + 8 * g);
  #pragma unroll
  for (int k2 = 0; k2 < 8; ++k2){
    int idx = tid + k2 * 512;
    int row = idx >> 6, c4 = idx & 63;
    *reinterpret_cast<uint2*>(xs_c + row * 512 + ((c4 * 8) ^ SWZ(row)))
        = make_uint2(pk2(vv[k2].x, vv[k2].y), pk2(vv[k2].z, vv[k2].w));
  }
  __syncthreads();

  const int  srcA = lo + 16 * ((2 * g) & 3);
  const int  srcB = lo + 16 * ((2 * g + 1) & 3);
  const bool ghi  = (g >= 2);

  // ---- pass 1: v (normal GEMM) -> vts LDS [d][t] swizzled ----
  {
    f32x4 avc[4][2];
    #pragma unroll
    for (int mt = 0; mt < 4; ++mt)
      #pragma unroll
      for (int nt = 0; nt < 2; ++nt) avc[mt][nt] = f32x4{0,0,0,0};

    #pragma unroll 1
    for (int kb = 0; kb < 2; ++kb){
      if (kb){   // chunk 1 weights (chunk 0 preloaded pre-barrier)
        #pragma unroll
        for (int nt = 0; nt < 2; ++nt)
          #pragma unroll
          for (int q4 = 0; q4 < 4; ++q4)
            wv[nt][q4] = *reinterpret_cast<const bf16x8*>(
                wqkvT + (size_t)(512 + h * 32 + 16 * nt + lo) * 256 + (4 + q4) * 32 + 8 * g);
      }
      #pragma unroll
      for (int q4 = 0; q4 < 4; ++q4){
        int kt = kb * 4 + q4;
        bf16x8 ax[4];
        #pragma unroll
        for (int mt = 0; mt < 4; ++mt){
          int row = 16 * mt + lo;
          ax[mt] = *reinterpret_cast<const bf16x8*>(xs_c + row * 512 + ((kt * 64 + 16 * g) ^ SWZ(row)));
        }
        #pragma unroll
        for (int nt = 0; nt < 2; ++nt)
          #pragma unroll
          for (int mt = 0; mt < 4; ++mt) avc[mt][nt] = mfma16(ax[mt], wv[nt][q4], avc[mt][nt]);
      }
    }
    // epilogue: +bias, store transposed+swizzled [d][t]
    #pragma unroll
    for (int nt = 0; nt < 2; ++nt){
      const float bvs = bqkv[512 + h * 32 + 16 * nt + lo];
      const int d = 16 * nt + lo;
      #pragma unroll
      for (int mt = 0; mt < 4; ++mt){
        f32x4 t = avc[mt][nt];
        *reinterpret_cast<uint2*>((char*)vts + h * 4096 + d * 128 + ((mt * 32 + g * 8) ^ SWZ(d)))
            = make_uint2(pk2(t[0] + bvs, t[1] + bvs), pk2(t[2] + bvs, t[3] + bvs));
      }
    }
  }

  // ---- pass 2: k AND q merged (transposed GEMMs, shared bx reads) ----
  bf16x8 fk[4], fq[4];   // K A-frags (j=lo,d=8g+e), Q B-frags (i=lo,d=8g+e)
  {
    f32x4 aq[2][4], akk[2][4];
    #pragma unroll
    for (int mt = 0; mt < 2; ++mt)
      #pragma unroll
      for (int nt = 0; nt < 4; ++nt){ aq[mt][nt] = f32x4{0,0,0,0}; akk[mt][nt] = f32x4{0,0,0,0}; }

    #pragma unroll 1
    for (int kb = 0; kb < 4; ++kb){
      bf16x8 wq2[2][2], wk2[2][2];
      #pragma unroll
      for (int mt = 0; mt < 2; ++mt)
        #pragma unroll
        for (int q2 = 0; q2 < 2; ++q2){
          wq2[mt][q2] = *reinterpret_cast<const bf16x8*>(
              wqkvT + (size_t)(h * 32 + 16 * mt + lo) * 256 + (kb * 2 + q2) * 32 + 8 * g);
          wk2[mt][q2] = *reinterpret_cast<const bf16x8*>(
              wqkvT + (size_t)(256 + h * 32 + 16 * mt + lo) * 256 + (kb * 2 + q2) * 32 + 8 * g);
        }
      #pragma unroll
      for (int q2 = 0; q2 < 2; ++q2){
        int kt = kb * 2 + q2;
        bf16x8 bx[4];
        #pragma unroll
        for (int nt = 0; nt < 4; ++nt){
          int row = 16 * nt + lo;
          bx[nt] = *reinterpret_cast<const bf16x8*>(xs_c + row * 512 + ((kt * 64 + 16 * g) ^ SWZ(row)));
        }
        #pragma unroll
        for (int mt = 0; mt < 2; ++mt)
          #pragma unroll
          for (int nt = 0; nt < 4; ++nt){
            aq[mt][nt]  = mfma16(wq2[mt][q2], bx[nt], aq[mt][nt]);
            akk[mt][nt] = mfma16(wk2[mt][q2], bx[nt], akk[mt][nt]);
          }
      }
    }
    uint32_t pq[2][4][2], pkk[2][4][2];
    #pragma unroll
    for (int mt = 0; mt < 2; ++mt){
      const float4 b4q = *reinterpret_cast<const float4*>(bqkv + h * 32 + 16 * mt + 4 * g);
      const float4 b4k = *reinterpret_cast<const float4*>(bqkv + 256 + h * 32 + 16 * mt + 4 * g);
      #pragma unroll
      for (int nt = 0; nt < 4; ++nt){
        f32x4 tq = aq[mt][nt], tk = akk[mt][nt];
        tq[0] += b4q.x; tq[1] += b4q.y; tq[2] += b4q.z; tq[3] += b4q.w;
        tk[0] += b4k.x; tk[1] += b4k.y; tk[2] += b4k.z; tk[3] += b4k.w;
        pq[mt][nt][0]  = pk2(tq[0], tq[1]); pq[mt][nt][1]  = pk2(tq[2], tq[3]);
        pkk[mt][nt][0] = pk2(tk[0], tk[1]); pkk[mt][nt][1] = pk2(tk[2], tk[3]);
      }
    }
    #pragma unroll
    for (int nt = 0; nt < 4; ++nt){
      fq[nt] = build_frag(pq[0][nt][0],  pq[0][nt][1],  pq[1][nt][0],  pq[1][nt][1],  srcA, srcB, ghi);
      fk[nt] = build_frag(pkk[0][nt][0], pkk[0][nt][1], pkk[1][nt][0], pkk[1][nt][1], srcA, srcB, ghi);
    }
  }
  __syncthreads();   // all xs reads done; attention overwrites xs with 'out'

  // ---- attention in nt-PAIRS: dual softmax chains, shared vb reads ----
  const char* vb = (const char*)vts + h * 4096;
  uint2 bb[4][4];   // [jt][nt] bias preload (L2), consumed progressively
  #pragma unroll
  for (int jt = 0; jt < 4; ++jt)
    #pragma unroll
    for (int nt = 0; nt < 4; ++nt)
      bb[jt][nt] = *reinterpret_cast<const uint2*>(
          biasP + h * 4096 + jt * 1024 + nt * 256 + (g * 16 + lo) * 4);

  #pragma unroll 1
  for (int pr = 0; pr < 2; ++pr){
    f32x4 lacc[2][4];            // [t2][jt]
    #pragma unroll
    for (int t2 = 0; t2 < 2; ++t2){
      const int nt = 2 * pr + t2;
      #pragma unroll
      for (int jt = 0; jt < 4; ++jt){
        lacc[t2][jt] = mfma16(fk[jt], fq[nt], f32x4{0,0,0,0});
        const uint2 bv2 = bb[jt][nt];
        lacc[t2][jt][0] += bf2f((unsigned short)(bv2.x & 0xffff));
        lacc[t2][jt][1] += bf2f((unsigned short)(bv2.x >> 16));
        lacc[t2][jt][2] += bf2f((unsigned short)(bv2.y & 0xffff));
        lacc[t2][jt][3] += bf2f((unsigned short)(bv2.y >> 16));
      }
    }
    // dual softmax (independent chains -> compiler interleaves)
    float m[2], ssum[2], r0[2];
    uint32_t pw[2][4][2];
    #pragma unroll
    for (int t2 = 0; t2 < 2; ++t2){
      m[t2] = -3.0e38f;
      #pragma unroll
      for (int jt = 0; jt < 4; ++jt)
        #pragma unroll
        for (int r = 0; r < 4; ++r) m[t2] = fmaxf(m[t2], lacc[t2][jt][r]);
    }
    #pragma unroll
    for (int t2 = 0; t2 < 2; ++t2){
      m[t2] = fmaxf(m[t2], __shfl_xor(m[t2], 16, 64));
      m[t2] = fmaxf(m[t2], __shfl_xor(m[t2], 32, 64));
    }
    #pragma unroll
    for (int t2 = 0; t2 < 2; ++t2){
      ssum[t2] = 0.f;
      #pragma unroll
      for (int jt = 0; jt < 4; ++jt){
        f32x4 t = lacc[t2][jt];
        #pragma unroll
        for (int r = 0; r < 4; ++r){
          t[r] = exp2f((t[r] - m[t2]) * 1.4426950408889634f);
          ssum[t2] += t[r];
        }
        pw[t2][jt][0] = pk2(t[0], t[1]);
        pw[t2][jt][1] = pk2(t[2], t[3]);
      }
    }
    #pragma unroll
    for (int t2 = 0; t2 < 2; ++t2){
      ssum[t2] += __shfl_xor(ssum[t2], 16, 64);
      ssum[t2] += __shfl_xor(ssum[t2], 32, 64);
      r0[t2] = 1.f / ssum[t2];
    }
    // P frags for both columns of the pair
    bf16x8 pf[2][2];
    #pragma unroll
    for (int t2 = 0; t2 < 2; ++t2){
      pf[t2][0] = build_frag(pw[t2][0][0], pw[t2][0][1], pw[t2][1][0], pw[t2][1][1], srcA, srcB, ghi);
      pf[t2][1] = build_frag(pw[t2][2][0], pw[t2][2][1], pw[t2][3][0], pw[t2][3][1], srcA, srcB, ghi);
    }
    // PV: vb reads shared across the pair
    #pragma unroll
    for (int dt = 0; dt < 2; ++dt){
      const int row = 16 * dt + lo;
      const bf16x8 av0 = *reinterpret_cast<const bf16x8*>(vb + row * 128 + ((16 * g) ^ SWZ(row)));
      const bf16x8 av1 = *reinterpret_cast<const bf16x8*>(vb + row * 128 + ((64 + 16 * g) ^ SWZ(row)));
      #pragma unroll
      for (int t2 = 0; t2 < 2; ++t2){
        const int i = 16 * (2 * pr + t2) + lo;
        f32x4 oacc = mfma16(av0, pf[t2][0], f32x4{0,0,0,0});
        oacc = mfma16(av1, pf[t2][1], oacc);
        *reinterpret_cast<uint2*>(xs_c + i * 512 + ((h * 64 + dt * 32 + g * 8) ^ SWZ(i)))
            = make_uint2(pk2(oacc[0] * r0[t2], oacc[1] * r0[t2]),
                         pk2(oacc[2] * r0[t2], oacc[3] * r0[t2]));
      }
    }
  }
  __syncthreads();

  // ---- final GEMM: y[i][c] = sum_hd out[i][hd] * wodT[c][hd] + bod[c] ----
  f32x4 facc[4][2];
  #pragma unroll
  for (int mt = 0; mt < 4; ++mt)
    #pragma unroll
    for (int nt = 0; nt < 2; ++nt) facc[mt][nt] = f32x4{0,0,0,0};

  #pragma unroll 1
  for (int kb = 0; kb < 2; ++kb){
    bf16x8 wod[2][4];
    #pragma unroll
    for (int nt = 0; nt < 2; ++nt)
      #pragma unroll
      for (int q4 = 0; q4 < 4; ++q4)
        wod[nt][q4] = *reinterpret_cast<const bf16x8*>(
            wodT + (size_t)(h * 32 + nt * 16 + lo) * 256 + (kb * 4 + q4) * 32 + 8 * g);
    #pragma unroll
    for (int q4 = 0; q4 < 4; ++q4){
      int kt = kb * 4 + q4;
      bf16x8 a[4];
      #pragma unroll
      for (int mt = 0; mt < 4; ++mt){
        int row = 16 * mt + lo;
        a[mt] = *reinterpret_cast<const bf16x8*>(xs_c + row * 512 + ((kt * 64 + 16 * g) ^ SWZ(row)));
      }
      #pragma unroll
      for (int nt = 0; nt < 2; ++nt)
        #pragma unroll
        for (int mt = 0; mt < 4; ++mt) facc[mt][nt] = mfma16(a[mt], wod[nt][q4], facc[mt][nt]);
    }
  }
  #pragma unroll
  for (int nt = 0; nt < 2; ++nt){
    int c = h * 32 + nt * 16 + lo;
    float bd = bod[c];
    #pragma unroll
    for (int mt = 0; mt < 4; ++mt)
      #pragma unroll
      for (int r = 0; r < 4; ++r){
        int i = 16 * mt + 4 * g + r;
        if (i < T) y[((size_t)b * T + i) * CCH + c] = facc[mt][nt][r] + bd;
      }
  }
}

// ---------------- launch ----------------
extern "C" void kernel_launch(void* const* d_in, const int* in_sizes, int n_in,
                              void* d_out, int out_size, void* d_ws, size_t ws_size,
                              hipStream_t stream){
  const float* x    = (const float*)d_in[0];
  const int*   rp   = (const int*)d_in[1];
  const float* btab = (const float*)d_in[2];
  const float* wq   = (const float*)d_in[3];
  const float* bq   = (const float*)d_in[4];
  const float* wk   = (const float*)d_in[5];
  const float* bk   = (const float*)d_in[6];
  const float* wv   = (const float*)d_in[7];
  const float* bv   = (const float*)d_in[8];
  const float* wo   = (const float*)d_in[9];
  const float* bo   = (const float*)d_in[10];
  const float* dw   = (const float*)d_in[11];
  const float* db   = (const float*)d_in[12];
  float* y = (float*)d_out;

  char* ws = (char*)d_ws;
  unsigned short* wqkvT = (unsigned short*)(ws);            // 393216 B
  unsigned short* wodT  = (unsigned short*)(ws + 393216);   // 131072 B
  unsigned short* biasP = (unsigned short*)(ws + 524288);   // 65536 B
  float* bqkv           = (float*)(ws + 589824);            // 3072 B
  float* bod            = (float*)(ws + 592896);            // 1024 B

  prep_wqkvT<<<768, 256, 0, stream>>>(wq, wk, wv, wqkvT);
  prep_wodT<<<256, 256, 0, stream>>>(wo, dw, wodT);
  prep_misc<<<9, 256, 0, stream>>>(rp, btab, bq, bk, bv, bo, dw, db, biasP, bqkv, bod);
  wmsa_main<<<1024, 512, 0, stream>>>(x, wqkvT, wodT, biasP, bqkv, bod, y);
}